// Round 2
// baseline (429.596 us; speedup 1.0000x reference)
//
#include <hip/hip_runtime.h>

typedef unsigned short ushort_t;
typedef __bf16 bf16x8 __attribute__((ext_vector_type(8)));
typedef float floatx4 __attribute__((ext_vector_type(4)));

#define B_WIN 192
#define NTOK 256
#define CDIM 256
#define NHEAD 8
#define HDIM 32
#define NWIN 64
#define MROWS (B_WIN * NTOK)   // 49152

__device__ __forceinline__ ushort_t f2bf(float f) {
  unsigned int u; __builtin_memcpy(&u, &f, 4);
  u = (u + 0x7fffu + ((u >> 16) & 1u)) >> 16;
  return (ushort_t)u;
}
__device__ __forceinline__ bf16x8 ldg8(const ushort_t* p) {
  return *reinterpret_cast<const bf16x8*>(p);
}

// ---------------- kernel 0: fp32 -> bf16 conversion (8 elems/thread) --------
__global__ __launch_bounds__(256) void cvt_f32_bf16(const float* __restrict__ src,
                                                    ushort_t* __restrict__ dst, int n8) {
  int t = blockIdx.x * 256 + threadIdx.x;
  if (t >= n8) return;
  const float4* s = reinterpret_cast<const float4*>(src) + (size_t)t * 2;
  float4 v0 = s[0], v1 = s[1];
  union { ushort_t u[8]; uint4 v; } pk;
  pk.u[0] = f2bf(v0.x); pk.u[1] = f2bf(v0.y); pk.u[2] = f2bf(v0.z); pk.u[3] = f2bf(v0.w);
  pk.u[4] = f2bf(v1.x); pk.u[5] = f2bf(v1.y); pk.u[6] = f2bf(v1.z); pk.u[7] = f2bf(v1.w);
  reinterpret_cast<uint4*>(dst)[t] = pk.v;
}

// ---------------- kernel 1: relative-position bias gather -> fp32 (H,N,N) ----
__global__ void bias_prep(const int* __restrict__ idx, const float* __restrict__ table,
                          float* __restrict__ bias) {
  int i = blockIdx.x;          // row token
  int j = threadIdx.x;         // col token
  int id = idx[i * 256 + j];
  #pragma unroll
  for (int h = 0; h < NHEAD; ++h)
    bias[h * 65536 + i * 256 + j] = table[id * NHEAD + h];
}

// ---------------- kernel 2: QKV GEMM  (M=49152, N=768, K=256), B^T input -----
// LDS-free: A/B bf16 fragments loaded straight from global (coalesced 16B/lane).
// Epilogue: +bias (fp32), q pre-scaled, scatter q/k (b,h,tok,d), vT (b,h,d,tok).
__global__ __launch_bounds__(256) void qkv_gemm(
    const ushort_t* __restrict__ x, const ushort_t* __restrict__ w,
    const float* __restrict__ qkvb, ushort_t* __restrict__ qws,
    ushort_t* __restrict__ kws, ushort_t* __restrict__ vtws) {
  const int lane = threadIdx.x & 63;
  const int wv = threadIdx.x >> 6;
  const int ln = lane & 15, qd = lane >> 4;
  const int row0 = blockIdx.x * 128 + (wv >> 1) * 64;
  const int col0 = blockIdx.y * 128 + (wv & 1) * 64;

  floatx4 acc[4][4];
  #pragma unroll
  for (int rt = 0; rt < 4; ++rt)
    #pragma unroll
    for (int ct = 0; ct < 4; ++ct)
      acc[rt][ct] = floatx4{0.f, 0.f, 0.f, 0.f};

  const ushort_t* ap = x + (size_t)(row0 + ln) * 256 + qd * 8;
  const ushort_t* bp = w + (size_t)(col0 + ln) * 256 + qd * 8;

  bf16x8 a[4], b[4], an[4], bn[4];
  #pragma unroll
  for (int t = 0; t < 4; ++t) {
    a[t] = ldg8(ap + t * 16 * 256);
    b[t] = ldg8(bp + t * 16 * 256);
  }
  #pragma unroll
  for (int kt = 0; kt < 8; ++kt) {
    if (kt < 7) {
      #pragma unroll
      for (int t = 0; t < 4; ++t) {
        an[t] = ldg8(ap + t * 16 * 256 + (kt + 1) * 32);
        bn[t] = ldg8(bp + t * 16 * 256 + (kt + 1) * 32);
      }
    }
    #pragma unroll
    for (int rt = 0; rt < 4; ++rt)
      #pragma unroll
      for (int ct = 0; ct < 4; ++ct)
        acc[rt][ct] = __builtin_amdgcn_mfma_f32_16x16x32_bf16(a[rt], b[ct], acc[rt][ct], 0, 0, 0);
    if (kt < 7) {
      #pragma unroll
      for (int t = 0; t < 4; ++t) { a[t] = an[t]; b[t] = bn[t]; }
    }
  }

  const int s = col0 >> 8;  // 0=q, 1=k, 2=v — uniform per wave (segments 256-wide)
  const float scl = 0.17677669529663687f;  // 1/sqrt(32)
  #pragma unroll
  for (int ct = 0; ct < 4; ++ct) {
    int colg = col0 + ct * 16 + ln;
    float bcol = qkvb[colg];
    int h = (colg >> 5) & 7;
    int d = colg & 31;
    #pragma unroll
    for (int rt = 0; rt < 4; ++rt) {
      int rbase = row0 + rt * 16 + qd * 4;
      int bwin = rbase >> 8;
      int tok = rbase & 255;
      if (s == 2) {
        union { ushort_t u[4]; uint2 v; } pk;
        #pragma unroll
        for (int i = 0; i < 4; ++i) pk.u[i] = f2bf(acc[rt][ct][i] + bcol);
        *reinterpret_cast<uint2*>(vtws + ((size_t)((bwin * 8 + h) * 32 + d) << 8) + tok) = pk.v;
      } else if (s == 0) {
        #pragma unroll
        for (int i = 0; i < 4; ++i)
          qws[((size_t)((bwin * 8 + h) * 256 + tok + i) << 5) + d] =
              f2bf((acc[rt][ct][i] + bcol) * scl);
      } else {
        #pragma unroll
        for (int i = 0; i < 4; ++i)
          kws[((size_t)((bwin * 8 + h) * 256 + tok + i) << 5) + d] =
              f2bf(acc[rt][ct][i] + bcol);
      }
    }
  }
}

// ---------------- kernel 3: windowed attention ------------------------------
// Block = 4 waves; wave owns a 16-row query strip; blockIdx.x = 64-row strip,
// blockIdx.y = (window, head). S strip 16x256 in registers (K=hd=32 -> 1 MFMA/tile).
__global__ __launch_bounds__(256) void attn_kernel(
    const ushort_t* __restrict__ qws, const ushort_t* __restrict__ kws,
    const ushort_t* __restrict__ vtws, const float* __restrict__ biasws,
    const float* __restrict__ mask, ushort_t* __restrict__ aows) {
  __shared__ __align__(16) ushort_t p_s[4][16][296];  // padded: stride 296 elems
  const int lane = threadIdx.x & 63;
  const int wv = threadIdx.x >> 6;
  const int ln = lane & 15, qd = lane >> 4;
  const int rb = blockIdx.x;       // 0..3
  const int bh = blockIdx.y;       // 0..1535
  const int bwin = bh >> 3, h = bh & 7;
  const int m0 = rb * 64 + wv * 16;

  const ushort_t* qb = qws + (size_t)bh * (256 * 32);
  const ushort_t* kb = kws + (size_t)bh * (256 * 32);
  const ushort_t* vtb = vtws + (size_t)bh * (32 * 256);

  // S = (q*scale) @ K^T   (q already scaled)
  bf16x8 aq = ldg8(qb + (m0 + ln) * 32 + qd * 8);
  floatx4 s[16];
  #pragma unroll
  for (int f = 0; f < 16; ++f) {
    bf16x8 bk = ldg8(kb + (f * 16 + ln) * 32 + qd * 8);
    floatx4 z = {0.f, 0.f, 0.f, 0.f};
    s[f] = __builtin_amdgcn_mfma_f32_16x16x32_bf16(aq, bk, z, 0, 0, 0);
  }

  // + bias + mask, row-softmax (row r held by 16-lane subgroup, reg i)
  const float* bp = biasws + h * 65536;
  const float* mp = mask + (size_t)(bwin & 63) * 65536;
  #pragma unroll
  for (int i = 0; i < 4; ++i) {
    int row = m0 + qd * 4 + i;
    int ro = row * 256 + ln;
    float mx = -1e30f;
    #pragma unroll
    for (int f = 0; f < 16; ++f) {
      float v = s[f][i] + bp[ro + f * 16] + mp[ro + f * 16];
      s[f][i] = v;
      mx = fmaxf(mx, v);
    }
    #pragma unroll
    for (int m = 1; m < 16; m <<= 1) mx = fmaxf(mx, __shfl_xor(mx, m, 16));
    float sum = 0.f;
    #pragma unroll
    for (int f = 0; f < 16; ++f) {
      float e = __expf(s[f][i] - mx);
      s[f][i] = e;
      sum += e;
    }
    #pragma unroll
    for (int m = 1; m < 16; m <<= 1) sum += __shfl_xor(sum, m, 16);
    float inv = 1.0f / sum;
    #pragma unroll
    for (int f = 0; f < 16; ++f)
      p_s[wv][qd * 4 + i][f * 16 + ln] = f2bf(s[f][i] * inv);
  }
  __syncthreads();

  // O = P @ V  : A from LDS (own strip), B from global vT (contiguous 16B)
  #pragma unroll
  for (int nt = 0; nt < 2; ++nt) {
    floatx4 o = {0.f, 0.f, 0.f, 0.f};
    #pragma unroll
    for (int kt = 0; kt < 8; ++kt) {
      bf16x8 apv = *reinterpret_cast<const bf16x8*>(&p_s[wv][ln][kt * 32 + qd * 8]);
      bf16x8 bv = ldg8(vtb + (nt * 16 + ln) * 256 + kt * 32 + qd * 8);
      o = __builtin_amdgcn_mfma_f32_16x16x32_bf16(apv, bv, o, 0, 0, 0);
    }
    #pragma unroll
    for (int i = 0; i < 4; ++i) {
      int tok = m0 + qd * 4 + i;
      aows[((size_t)(bwin * 256 + tok) << 8) + h * 32 + nt * 16 + ln] = f2bf(o[i]);
    }
  }
}

// ---------------- kernel 4: output projection (M=49152, N=256, K=256) -------
__global__ __launch_bounds__(256) void proj_gemm(
    const ushort_t* __restrict__ a_, const ushort_t* __restrict__ w,
    const float* __restrict__ pb, float* __restrict__ out) {
  const int lane = threadIdx.x & 63;
  const int wv = threadIdx.x >> 6;
  const int ln = lane & 15, qd = lane >> 4;
  const int row0 = blockIdx.x * 128 + (wv >> 1) * 64;
  const int col0 = blockIdx.y * 128 + (wv & 1) * 64;

  floatx4 acc[4][4];
  #pragma unroll
  for (int rt = 0; rt < 4; ++rt)
    #pragma unroll
    for (int ct = 0; ct < 4; ++ct)
      acc[rt][ct] = floatx4{0.f, 0.f, 0.f, 0.f};

  const ushort_t* ap = a_ + (size_t)(row0 + ln) * 256 + qd * 8;
  const ushort_t* bp = w + (size_t)(col0 + ln) * 256 + qd * 8;

  bf16x8 a[4], b[4], an[4], bn[4];
  #pragma unroll
  for (int t = 0; t < 4; ++t) {
    a[t] = ldg8(ap + t * 16 * 256);
    b[t] = ldg8(bp + t * 16 * 256);
  }
  #pragma unroll
  for (int kt = 0; kt < 8; ++kt) {
    if (kt < 7) {
      #pragma unroll
      for (int t = 0; t < 4; ++t) {
        an[t] = ldg8(ap + t * 16 * 256 + (kt + 1) * 32);
        bn[t] = ldg8(bp + t * 16 * 256 + (kt + 1) * 32);
      }
    }
    #pragma unroll
    for (int rt = 0; rt < 4; ++rt)
      #pragma unroll
      for (int ct = 0; ct < 4; ++ct)
        acc[rt][ct] = __builtin_amdgcn_mfma_f32_16x16x32_bf16(a[rt], b[ct], acc[rt][ct], 0, 0, 0);
    if (kt < 7) {
      #pragma unroll
      for (int t = 0; t < 4; ++t) { a[t] = an[t]; b[t] = bn[t]; }
    }
  }

  #pragma unroll
  for (int ct = 0; ct < 4; ++ct) {
    int colg = col0 + ct * 16 + ln;
    float bcol = pb[colg];
    #pragma unroll
    for (int rt = 0; rt < 4; ++rt) {
      int rbase = row0 + rt * 16 + qd * 4;
      #pragma unroll
      for (int i = 0; i < 4; ++i)
        out[(size_t)(rbase + i) * 256 + colg] = acc[rt][ct][i] + bcol;
    }
  }
}

// ---------------- launch ----------------------------------------------------
extern "C" void kernel_launch(void* const* d_in, const int* in_sizes, int n_in,
                              void* d_out, int out_size, void* d_ws, size_t ws_size,
                              hipStream_t stream) {
  const float* x      = (const float*)d_in[0];
  const float* mask   = (const float*)d_in[1];
  const float* qkv_w  = (const float*)d_in[2];
  const float* qkv_b  = (const float*)d_in[3];
  const float* proj_w = (const float*)d_in[4];
  const float* proj_b = (const float*)d_in[5];
  const float* table  = (const float*)d_in[6];
  const int*   idx    = (const int*)d_in[7];
  float* out = (float*)d_out;

  char* ws = (char*)d_ws;
  const size_t SZ = (size_t)MROWS * CDIM * 2;  // 25165824 bytes per bf16 buffer
  ushort_t* xbf  = (ushort_t*)(ws);
  ushort_t* qws  = (ushort_t*)(ws + SZ);
  ushort_t* kws  = (ushort_t*)(ws + 2 * SZ);
  ushort_t* vtws = (ushort_t*)(ws + 3 * SZ);
  ushort_t* aows = (ushort_t*)(ws + 4 * SZ);
  float*  biasws = (float*)(ws + 5 * SZ);                       // 2 MB fp32 (H,N,N)
  ushort_t* wqkvbf  = (ushort_t*)(ws + 5 * SZ + 2097152);       // 768x256 bf16
  ushort_t* wprojbf = (ushort_t*)(ws + 5 * SZ + 2097152 + 393216);  // 256x256 bf16

  cvt_f32_bf16<<<dim3(6144), dim3(256), 0, stream>>>(x, xbf, 12582912 / 8);
  cvt_f32_bf16<<<dim3(96),   dim3(256), 0, stream>>>(qkv_w, wqkvbf, 196608 / 8);
  cvt_f32_bf16<<<dim3(32),   dim3(256), 0, stream>>>(proj_w, wprojbf, 65536 / 8);
  bias_prep<<<dim3(256), dim3(256), 0, stream>>>(idx, table, biasws);
  qkv_gemm<<<dim3(384, 6), dim3(256), 0, stream>>>(xbf, wqkvbf, qkv_b, qws, kws, vtws);
  attn_kernel<<<dim3(4, 1536), dim3(256), 0, stream>>>(qws, kws, vtws, biasws, mask, aows);
  proj_gemm<<<dim3(384, 2), dim3(256), 0, stream>>>(aows, wprojbf, proj_b, out);
}

// Round 3
// 382.385 us; speedup vs baseline: 1.1235x; 1.1235x over previous
//
#include <hip/hip_runtime.h>

typedef unsigned short ushort_t;
typedef __bf16 bf16x8 __attribute__((ext_vector_type(8)));
typedef float floatx4 __attribute__((ext_vector_type(4)));

#define B_WIN 192
#define NTOK 256
#define CDIM 256
#define NHEAD 8
#define HDIM 32
#define NWIN 64
#define MROWS (B_WIN * NTOK)   // 49152

__device__ __forceinline__ float bf2f(unsigned int b) {
  unsigned int u = (b & 0xffffu) << 16;
  float f; __builtin_memcpy(&f, &u, 4); return f;
}
__device__ __forceinline__ ushort_t f2bf(float f) {
  unsigned int u; __builtin_memcpy(&u, &f, 4);
  u = (u + 0x7fffu + ((u >> 16) & 1u)) >> 16;
  return (ushort_t)u;
}
__device__ __forceinline__ bf16x8 ldg8(const ushort_t* p) {
  return *reinterpret_cast<const bf16x8*>(p);
}

// ---------------- kernel 0: fp32 -> bf16 conversion (8 elems/thread) --------
__global__ __launch_bounds__(256) void cvt_f32_bf16(const float* __restrict__ src,
                                                    ushort_t* __restrict__ dst, int n8) {
  int t = blockIdx.x * 256 + threadIdx.x;
  if (t >= n8) return;
  const float4* s = reinterpret_cast<const float4*>(src) + (size_t)t * 2;
  float4 v0 = s[0], v1 = s[1];
  union { ushort_t u[8]; uint4 v; } pk;
  pk.u[0] = f2bf(v0.x); pk.u[1] = f2bf(v0.y); pk.u[2] = f2bf(v0.z); pk.u[3] = f2bf(v0.w);
  pk.u[4] = f2bf(v1.x); pk.u[5] = f2bf(v1.y); pk.u[6] = f2bf(v1.z); pk.u[7] = f2bf(v1.w);
  reinterpret_cast<uint4*>(dst)[t] = pk.v;
}

// ---------------- kernel 1: combined bias+mask, transposed bf16 -------------
// bm[win][h][col][row] = bias(h,row,col) + mask(win,row,col), bf16.
// Transposed layout lets attn load 4 consecutive rows per lane as one uint2.
__global__ __launch_bounds__(256) void bm_prep(const int* __restrict__ idx,
                                               const float* __restrict__ table,
                                               const float* __restrict__ mask,
                                               ushort_t* __restrict__ bm) {
  int win = blockIdx.x;     // 0..63
  int col = blockIdx.y;     // 0..255
  int row = threadIdx.x;    // 0..255
  int id = idx[row * 256 + col];
  float mval = mask[((size_t)(win * 256 + row) << 8) + col];
  #pragma unroll
  for (int h = 0; h < NHEAD; ++h) {
    float b = table[id * NHEAD + h];
    bm[((((size_t)win * NHEAD + h) * 256 + col) << 8) + row] = f2bf(b + mval);
  }
}

// ---------------- kernel 2: QKV GEMM  (M=49152, N=768, K=256), B^T input -----
__global__ __launch_bounds__(256) void qkv_gemm(
    const ushort_t* __restrict__ x, const ushort_t* __restrict__ w,
    const float* __restrict__ qkvb, ushort_t* __restrict__ qws,
    ushort_t* __restrict__ kws, ushort_t* __restrict__ vtws) {
  const int lane = threadIdx.x & 63;
  const int wv = threadIdx.x >> 6;
  const int ln = lane & 15, qd = lane >> 4;
  const int row0 = blockIdx.x * 128 + (wv >> 1) * 64;
  const int col0 = blockIdx.y * 128 + (wv & 1) * 64;

  floatx4 acc[4][4];
  #pragma unroll
  for (int rt = 0; rt < 4; ++rt)
    #pragma unroll
    for (int ct = 0; ct < 4; ++ct)
      acc[rt][ct] = floatx4{0.f, 0.f, 0.f, 0.f};

  const ushort_t* ap = x + (size_t)(row0 + ln) * 256 + qd * 8;
  const ushort_t* bp = w + (size_t)(col0 + ln) * 256 + qd * 8;

  bf16x8 a[4], b[4], an[4], bn[4];
  #pragma unroll
  for (int t = 0; t < 4; ++t) {
    a[t] = ldg8(ap + t * 16 * 256);
    b[t] = ldg8(bp + t * 16 * 256);
  }
  #pragma unroll
  for (int kt = 0; kt < 8; ++kt) {
    if (kt < 7) {
      #pragma unroll
      for (int t = 0; t < 4; ++t) {
        an[t] = ldg8(ap + t * 16 * 256 + (kt + 1) * 32);
        bn[t] = ldg8(bp + t * 16 * 256 + (kt + 1) * 32);
      }
    }
    #pragma unroll
    for (int rt = 0; rt < 4; ++rt)
      #pragma unroll
      for (int ct = 0; ct < 4; ++ct)
        acc[rt][ct] = __builtin_amdgcn_mfma_f32_16x16x32_bf16(a[rt], b[ct], acc[rt][ct], 0, 0, 0);
    if (kt < 7) {
      #pragma unroll
      for (int t = 0; t < 4; ++t) { a[t] = an[t]; b[t] = bn[t]; }
    }
  }

  const int s = col0 >> 8;  // 0=q, 1=k, 2=v — uniform per wave
  const float scl = 0.17677669529663687f;  // 1/sqrt(32)
  #pragma unroll
  for (int ct = 0; ct < 4; ++ct) {
    int colg = col0 + ct * 16 + ln;
    float bcol = qkvb[colg];
    int h = (colg >> 5) & 7;
    int d = colg & 31;
    #pragma unroll
    for (int rt = 0; rt < 4; ++rt) {
      int rbase = row0 + rt * 16 + qd * 4;
      int bwin = rbase >> 8;
      int tok = rbase & 255;
      if (s == 2) {
        union { ushort_t u[4]; uint2 v; } pk;
        #pragma unroll
        for (int i = 0; i < 4; ++i) pk.u[i] = f2bf(acc[rt][ct][i] + bcol);
        *reinterpret_cast<uint2*>(vtws + ((size_t)((bwin * 8 + h) * 32 + d) << 8) + tok) = pk.v;
      } else if (s == 0) {
        #pragma unroll
        for (int i = 0; i < 4; ++i)
          qws[((size_t)((bwin * 8 + h) * 256 + tok + i) << 5) + d] =
              f2bf((acc[rt][ct][i] + bcol) * scl);
      } else {
        #pragma unroll
        for (int i = 0; i < 4; ++i)
          kws[((size_t)((bwin * 8 + h) * 256 + tok + i) << 5) + d] =
              f2bf(acc[rt][ct][i] + bcol);
      }
    }
  }
}

// ---------------- kernel 3: windowed attention ------------------------------
// Block = 4 waves; wave owns a 16-row query strip; blockIdx.x = 64-row strip,
// blockIdx.y = (window, head). S strip 16x256 in registers.
__global__ __launch_bounds__(256) void attn_kernel(
    const ushort_t* __restrict__ qws, const ushort_t* __restrict__ kws,
    const ushort_t* __restrict__ vtws, const ushort_t* __restrict__ bm,
    ushort_t* __restrict__ aows) {
  __shared__ __align__(16) ushort_t p_s[4][16][296];  // padded stride
  const int lane = threadIdx.x & 63;
  const int wv = threadIdx.x >> 6;
  const int ln = lane & 15, qd = lane >> 4;
  const int rb = blockIdx.x;       // 0..3
  const int bh = blockIdx.y;       // 0..1535
  const int bwin = bh >> 3, h = bh & 7;
  const int m0 = rb * 64 + wv * 16;

  const ushort_t* qb = qws + (size_t)bh * (256 * 32);
  const ushort_t* kb = kws + (size_t)bh * (256 * 32);
  const ushort_t* vtb = vtws + (size_t)bh * (32 * 256);
  const ushort_t* bmp = bm + ((size_t)((bwin & 63) * NHEAD + h) << 16);

  // S = (q*scale) @ K^T   (q already scaled)
  bf16x8 aq = ldg8(qb + (m0 + ln) * 32 + qd * 8);
  floatx4 s[16];
  #pragma unroll
  for (int f = 0; f < 16; ++f) {
    bf16x8 bk = ldg8(kb + (f * 16 + ln) * 32 + qd * 8);
    floatx4 z = {0.f, 0.f, 0.f, 0.f};
    s[f] = __builtin_amdgcn_mfma_f32_16x16x32_bf16(aq, bk, z, 0, 0, 0);
  }

  // + (bias+mask) from transposed bf16: one uint2 = 4 consecutive rows
  #pragma unroll
  for (int f = 0; f < 16; ++f) {
    uint2 raw = *reinterpret_cast<const uint2*>(bmp + (((f * 16 + ln) << 8) + m0 + qd * 4));
    s[f][0] += bf2f(raw.x);
    s[f][1] += bf2f(raw.x >> 16);
    s[f][2] += bf2f(raw.y);
    s[f][3] += bf2f(raw.y >> 16);
  }

  // row-softmax (row r held by 16-lane subgroup, reg i)
  #pragma unroll
  for (int i = 0; i < 4; ++i) {
    float mx = -1e30f;
    #pragma unroll
    for (int f = 0; f < 16; ++f) mx = fmaxf(mx, s[f][i]);
    #pragma unroll
    for (int m = 1; m < 16; m <<= 1) mx = fmaxf(mx, __shfl_xor(mx, m, 16));
    float sum = 0.f;
    #pragma unroll
    for (int f = 0; f < 16; ++f) {
      float e = __expf(s[f][i] - mx);
      s[f][i] = e;
      sum += e;
    }
    #pragma unroll
    for (int m = 1; m < 16; m <<= 1) sum += __shfl_xor(sum, m, 16);
    float inv = 1.0f / sum;
    #pragma unroll
    for (int f = 0; f < 16; ++f)
      p_s[wv][qd * 4 + i][f * 16 + ln] = f2bf(s[f][i] * inv);
  }
  // no __syncthreads(): each wave reads only its own p_s[wv] strip;
  // intra-wave ds_write->ds_read ordering is handled by lgkmcnt waits.

  // O = P @ V  : A from LDS (own strip), B from global vT (contiguous 16B)
  #pragma unroll
  for (int nt = 0; nt < 2; ++nt) {
    floatx4 o = {0.f, 0.f, 0.f, 0.f};
    #pragma unroll
    for (int kt = 0; kt < 8; ++kt) {
      bf16x8 apv = *reinterpret_cast<const bf16x8*>(&p_s[wv][ln][kt * 32 + qd * 8]);
      bf16x8 bv = ldg8(vtb + (nt * 16 + ln) * 256 + kt * 32 + qd * 8);
      o = __builtin_amdgcn_mfma_f32_16x16x32_bf16(apv, bv, o, 0, 0, 0);
    }
    #pragma unroll
    for (int i = 0; i < 4; ++i) {
      int tok = m0 + qd * 4 + i;
      aows[((size_t)(bwin * 256 + tok) << 8) + h * 32 + nt * 16 + ln] = f2bf(o[i]);
    }
  }
}

// ---------------- kernel 4: output projection (M=49152, N=256, K=256) -------
__global__ __launch_bounds__(256) void proj_gemm(
    const ushort_t* __restrict__ a_, const ushort_t* __restrict__ w,
    const float* __restrict__ pb, float* __restrict__ out) {
  const int lane = threadIdx.x & 63;
  const int wv = threadIdx.x >> 6;
  const int ln = lane & 15, qd = lane >> 4;
  const int row0 = blockIdx.x * 128 + (wv >> 1) * 64;
  const int col0 = blockIdx.y * 128 + (wv & 1) * 64;

  floatx4 acc[4][4];
  #pragma unroll
  for (int rt = 0; rt < 4; ++rt)
    #pragma unroll
    for (int ct = 0; ct < 4; ++ct)
      acc[rt][ct] = floatx4{0.f, 0.f, 0.f, 0.f};

  const ushort_t* ap = a_ + (size_t)(row0 + ln) * 256 + qd * 8;
  const ushort_t* bp = w + (size_t)(col0 + ln) * 256 + qd * 8;

  bf16x8 a[4], b[4], an[4], bn[4];
  #pragma unroll
  for (int t = 0; t < 4; ++t) {
    a[t] = ldg8(ap + t * 16 * 256);
    b[t] = ldg8(bp + t * 16 * 256);
  }
  #pragma unroll
  for (int kt = 0; kt < 8; ++kt) {
    if (kt < 7) {
      #pragma unroll
      for (int t = 0; t < 4; ++t) {
        an[t] = ldg8(ap + t * 16 * 256 + (kt + 1) * 32);
        bn[t] = ldg8(bp + t * 16 * 256 + (kt + 1) * 32);
      }
    }
    #pragma unroll
    for (int rt = 0; rt < 4; ++rt)
      #pragma unroll
      for (int ct = 0; ct < 4; ++ct)
        acc[rt][ct] = __builtin_amdgcn_mfma_f32_16x16x32_bf16(a[rt], b[ct], acc[rt][ct], 0, 0, 0);
    if (kt < 7) {
      #pragma unroll
      for (int t = 0; t < 4; ++t) { a[t] = an[t]; b[t] = bn[t]; }
    }
  }

  #pragma unroll
  for (int ct = 0; ct < 4; ++ct) {
    int colg = col0 + ct * 16 + ln;
    float bcol = pb[colg];
    #pragma unroll
    for (int rt = 0; rt < 4; ++rt) {
      int rbase = row0 + rt * 16 + qd * 4;
      #pragma unroll
      for (int i = 0; i < 4; ++i)
        out[(size_t)(rbase + i) * 256 + colg] = acc[rt][ct][i] + bcol;
    }
  }
}

// ---------------- launch ----------------------------------------------------
extern "C" void kernel_launch(void* const* d_in, const int* in_sizes, int n_in,
                              void* d_out, int out_size, void* d_ws, size_t ws_size,
                              hipStream_t stream) {
  const float* x      = (const float*)d_in[0];
  const float* mask   = (const float*)d_in[1];
  const float* qkv_w  = (const float*)d_in[2];
  const float* qkv_b  = (const float*)d_in[3];
  const float* proj_w = (const float*)d_in[4];
  const float* proj_b = (const float*)d_in[5];
  const float* table  = (const float*)d_in[6];
  const int*   idx    = (const int*)d_in[7];
  float* out = (float*)d_out;

  char* ws = (char*)d_ws;
  const size_t SZ = (size_t)MROWS * CDIM * 2;  // 25165824 B per bf16 buffer
  ushort_t* xbf  = (ushort_t*)(ws);
  ushort_t* qws  = (ushort_t*)(ws + SZ);
  ushort_t* kws  = (ushort_t*)(ws + 2 * SZ);
  ushort_t* vtws = (ushort_t*)(ws + 3 * SZ);
  ushort_t* aows = (ushort_t*)(ws + 4 * SZ);
  ushort_t* bmws = (ushort_t*)(ws + 5 * SZ);                    // 64 MB bf16 (w,h,col,row)
  ushort_t* wqkvbf  = (ushort_t*)(ws + 5 * SZ + 67108864);      // 768x256 bf16
  ushort_t* wprojbf = (ushort_t*)(ws + 5 * SZ + 67108864 + 393216);

  cvt_f32_bf16<<<dim3(6144), dim3(256), 0, stream>>>(x, xbf, 12582912 / 8);
  cvt_f32_bf16<<<dim3(96),   dim3(256), 0, stream>>>(qkv_w, wqkvbf, 196608 / 8);
  cvt_f32_bf16<<<dim3(32),   dim3(256), 0, stream>>>(proj_w, wprojbf, 65536 / 8);
  bm_prep<<<dim3(64, 256), dim3(256), 0, stream>>>(idx, table, mask, bmws);
  qkv_gemm<<<dim3(384, 6), dim3(256), 0, stream>>>(xbf, wqkvbf, qkv_b, qws, kws, vtws);
  attn_kernel<<<dim3(4, 1536), dim3(256), 0, stream>>>(qws, kws, vtws, bmws, aows);
  proj_gemm<<<dim3(384, 2), dim3(256), 0, stream>>>(aows, wprojbf, proj_b, out);
}

// Round 4
// 372.267 us; speedup vs baseline: 1.1540x; 1.0272x over previous
//
#include <hip/hip_runtime.h>

typedef unsigned short ushort_t;
typedef __bf16 bf16x8 __attribute__((ext_vector_type(8)));
typedef float floatx4 __attribute__((ext_vector_type(4)));

#define B_WIN 192
#define NTOK 256
#define CDIM 256
#define NHEAD 8
#define HDIM 32
#define NWIN 64
#define MROWS (B_WIN * NTOK)   // 49152

__device__ __forceinline__ float bf2f(unsigned int b) {
  unsigned int u = (b & 0xffffu) << 16;
  float f; __builtin_memcpy(&f, &u, 4); return f;
}
__device__ __forceinline__ ushort_t f2bf(float f) {
  unsigned int u; __builtin_memcpy(&u, &f, 4);
  u = (u + 0x7fffu + ((u >> 16) & 1u)) >> 16;
  return (ushort_t)u;
}
__device__ __forceinline__ bf16x8 ldg8(const ushort_t* p) {
  return *reinterpret_cast<const bf16x8*>(p);
}

// ---------------- kernel 0: fp32 -> bf16 conversion (8 elems/thread) --------
__global__ __launch_bounds__(256) void cvt_f32_bf16(const float* __restrict__ src,
                                                    ushort_t* __restrict__ dst, int n8) {
  int t = blockIdx.x * 256 + threadIdx.x;
  if (t >= n8) return;
  const float4* s = reinterpret_cast<const float4*>(src) + (size_t)t * 2;
  float4 v0 = s[0], v1 = s[1];
  union { ushort_t u[8]; uint4 v; } pk;
  pk.u[0] = f2bf(v0.x); pk.u[1] = f2bf(v0.y); pk.u[2] = f2bf(v0.z); pk.u[3] = f2bf(v0.w);
  pk.u[4] = f2bf(v1.x); pk.u[5] = f2bf(v1.y); pk.u[6] = f2bf(v1.z); pk.u[7] = f2bf(v1.w);
  reinterpret_cast<uint4*>(dst)[t] = pk.v;
}

// ---------------- kernel 1: combined bias+mask, NATURAL layout bf16 ---------
// bm[win][h][row][col] = bias(h,row,col) + mask(win,row,col).  All accesses
// coalesced; single fp32 add then one bf16 rounding.
__global__ __launch_bounds__(256) void bm_prep(const int* __restrict__ idx,
                                               const float* __restrict__ table,
                                               const float* __restrict__ mask,
                                               ushort_t* __restrict__ bm) {
  int win = blockIdx.x;     // 0..63
  int row = blockIdx.y;     // 0..255
  int col = threadIdx.x;    // 0..255
  int id = idx[row * 256 + col];
  float mval = mask[((size_t)(win * 256 + row) << 8) + col];
  #pragma unroll
  for (int h = 0; h < NHEAD; ++h) {
    float b = table[id * NHEAD + h];
    bm[((((size_t)win * NHEAD + h) * 256 + row) << 8) + col] = f2bf(b + mval);
  }
}

// ---------------- kernel 2: QKV GEMM  (M=49152, N=768, K=256), B^T input -----
__global__ __launch_bounds__(256) void qkv_gemm(
    const ushort_t* __restrict__ x, const ushort_t* __restrict__ w,
    const float* __restrict__ qkvb, ushort_t* __restrict__ qws,
    ushort_t* __restrict__ kws, ushort_t* __restrict__ vtws) {
  const int lane = threadIdx.x & 63;
  const int wv = threadIdx.x >> 6;
  const int ln = lane & 15, qd = lane >> 4;
  const int row0 = blockIdx.x * 128 + (wv >> 1) * 64;
  const int col0 = blockIdx.y * 128 + (wv & 1) * 64;

  floatx4 acc[4][4];
  #pragma unroll
  for (int rt = 0; rt < 4; ++rt)
    #pragma unroll
    for (int ct = 0; ct < 4; ++ct)
      acc[rt][ct] = floatx4{0.f, 0.f, 0.f, 0.f};

  const ushort_t* ap = x + (size_t)(row0 + ln) * 256 + qd * 8;
  const ushort_t* bp = w + (size_t)(col0 + ln) * 256 + qd * 8;

  bf16x8 a[4], b[4], an[4], bn[4];
  #pragma unroll
  for (int t = 0; t < 4; ++t) {
    a[t] = ldg8(ap + t * 16 * 256);
    b[t] = ldg8(bp + t * 16 * 256);
  }
  #pragma unroll
  for (int kt = 0; kt < 8; ++kt) {
    if (kt < 7) {
      #pragma unroll
      for (int t = 0; t < 4; ++t) {
        an[t] = ldg8(ap + t * 16 * 256 + (kt + 1) * 32);
        bn[t] = ldg8(bp + t * 16 * 256 + (kt + 1) * 32);
      }
    }
    #pragma unroll
    for (int rt = 0; rt < 4; ++rt)
      #pragma unroll
      for (int ct = 0; ct < 4; ++ct)
        acc[rt][ct] = __builtin_amdgcn_mfma_f32_16x16x32_bf16(a[rt], b[ct], acc[rt][ct], 0, 0, 0);
    if (kt < 7) {
      #pragma unroll
      for (int t = 0; t < 4; ++t) { a[t] = an[t]; b[t] = bn[t]; }
    }
  }

  const int s = col0 >> 8;  // 0=q, 1=k, 2=v — uniform per wave
  const float scl = 0.17677669529663687f;  // 1/sqrt(32)
  #pragma unroll
  for (int ct = 0; ct < 4; ++ct) {
    int colg = col0 + ct * 16 + ln;
    float bcol = qkvb[colg];
    int h = (colg >> 5) & 7;
    int d = colg & 31;
    #pragma unroll
    for (int rt = 0; rt < 4; ++rt) {
      int rbase = row0 + rt * 16 + qd * 4;
      int bwin = rbase >> 8;
      int tok = rbase & 255;
      if (s == 2) {
        union { ushort_t u[4]; uint2 v; } pk;
        #pragma unroll
        for (int i = 0; i < 4; ++i) pk.u[i] = f2bf(acc[rt][ct][i] + bcol);
        *reinterpret_cast<uint2*>(vtws + ((size_t)((bwin * 8 + h) * 32 + d) << 8) + tok) = pk.v;
      } else if (s == 0) {
        #pragma unroll
        for (int i = 0; i < 4; ++i)
          qws[((size_t)((bwin * 8 + h) * 256 + tok + i) << 5) + d] =
              f2bf((acc[rt][ct][i] + bcol) * scl);
      } else {
        #pragma unroll
        for (int i = 0; i < 4; ++i)
          kws[((size_t)((bwin * 8 + h) * 256 + tok + i) << 5) + d] =
              f2bf(acc[rt][ct][i] + bcol);
      }
    }
  }
}

// ---------------- kernel 3: windowed attention, S^T formulation -------------
// One block per (win,h); 8 waves; loop over 3 batch-windows x 2 row-halves.
// mfma(k_frag, q_frag) gives S^T in C-layout: col=ln -> q-row, row=qd*4+i ->
// k-col. Lane holds 64 k-contiguous logits of ONE q-row: uint2 bm loads in
// natural layout, in-lane softmax, packed b64 LDS transpose, deferred norm.
__global__ __launch_bounds__(512, 4) void attn_kernel(
    const ushort_t* __restrict__ qws, const ushort_t* __restrict__ kws,
    const ushort_t* __restrict__ vtws, const ushort_t* __restrict__ bm,
    ushort_t* __restrict__ aows) {
  __shared__ __align__(16) ushort_t p_s[8][16][264];  // 67584 B
  const int lane = threadIdx.x & 63;
  const int wv = threadIdx.x >> 6;          // 0..7
  const int ln = lane & 15, qd = lane >> 4;
  const int win = blockIdx.x >> 3, h = blockIdx.x & 7;
  const ushort_t* bmp = bm + ((size_t)(win * NHEAD + h) << 16);

  for (int it = 0; it < 6; ++it) {
    const int batch = it >> 1;              // 0..2
    const int m0 = (it & 1) * 128 + wv * 16;
    const int bwin = batch * 64 + win;
    const int bh = bwin * 8 + h;
    const ushort_t* qb = qws + (size_t)bh * (256 * 32);
    const ushort_t* kb = kws + (size_t)bh * (256 * 32);
    const ushort_t* vtb = vtws + (size_t)bh * (32 * 256);

    // S^T tiles: st[f][i] = S[q = m0+ln][k = f*16 + qd*4 + i]
    bf16x8 qf = ldg8(qb + (m0 + ln) * 32 + qd * 8);
    floatx4 st[16];
    #pragma unroll
    for (int f = 0; f < 16; ++f) {
      bf16x8 kf = ldg8(kb + (f * 16 + ln) * 32 + qd * 8);
      floatx4 z = {0.f, 0.f, 0.f, 0.f};
      st[f] = __builtin_amdgcn_mfma_f32_16x16x32_bf16(kf, qf, z, 0, 0, 0);
    }

    // + (bias+mask): natural layout, 4 k-consecutive bf16 per uint2
    const ushort_t* bmr = bmp + ((m0 + ln) << 8);
    #pragma unroll
    for (int f = 0; f < 16; ++f) {
      uint2 raw = *reinterpret_cast<const uint2*>(bmr + f * 16 + qd * 4);
      st[f][0] += bf2f(raw.x);
      st[f][1] += bf2f(raw.x >> 16);
      st[f][2] += bf2f(raw.y);
      st[f][3] += bf2f(raw.y >> 16);
    }

    // row softmax: in-lane reduce over 64 vals + xor-16/32 across qd groups
    float mx = -1e30f;
    #pragma unroll
    for (int f = 0; f < 16; ++f) {
      mx = fmaxf(mx, fmaxf(fmaxf(st[f][0], st[f][1]), fmaxf(st[f][2], st[f][3])));
    }
    mx = fmaxf(mx, __shfl_xor(mx, 16, 64));
    mx = fmaxf(mx, __shfl_xor(mx, 32, 64));
    float sum = 0.f;
    #pragma unroll
    for (int f = 0; f < 16; ++f) {
      #pragma unroll
      for (int i = 0; i < 4; ++i) {
        float e = __expf(st[f][i] - mx);
        st[f][i] = e;
        sum += e;
      }
    }
    sum += __shfl_xor(sum, 16, 64);
    sum += __shfl_xor(sum, 32, 64);
    float inv = 1.0f / sum;   // applied post-PV

    // pack unnormalized P quartets (k-contiguous) -> LDS row-major [q][k]
    #pragma unroll
    for (int f = 0; f < 16; ++f) {
      union { ushort_t u[4]; uint2 v; } pk;
      pk.u[0] = f2bf(st[f][0]); pk.u[1] = f2bf(st[f][1]);
      pk.u[2] = f2bf(st[f][2]); pk.u[3] = f2bf(st[f][3]);
      *reinterpret_cast<uint2*>(&p_s[wv][ln][f * 16 + qd * 4]) = pk.v;
    }
    // own-strip read only: intra-wave lgkmcnt ordering, no __syncthreads

    bf16x8 apv[8];
    #pragma unroll
    for (int kt = 0; kt < 8; ++kt)
      apv[kt] = *reinterpret_cast<const bf16x8*>(&p_s[wv][ln][kt * 32 + qd * 8]);

    float invr[4];
    #pragma unroll
    for (int i = 0; i < 4; ++i) invr[i] = __shfl(inv, qd * 4 + i, 16);

    #pragma unroll
    for (int nt = 0; nt < 2; ++nt) {
      floatx4 o = {0.f, 0.f, 0.f, 0.f};
      #pragma unroll
      for (int kt = 0; kt < 8; ++kt) {
        bf16x8 bv = ldg8(vtb + (nt * 16 + ln) * 256 + kt * 32 + qd * 8);
        o = __builtin_amdgcn_mfma_f32_16x16x32_bf16(apv[kt], bv, o, 0, 0, 0);
      }
      #pragma unroll
      for (int i = 0; i < 4; ++i) {
        int tok = m0 + qd * 4 + i;
        aows[((size_t)(bwin * 256 + tok) << 8) + h * 32 + nt * 16 + ln] =
            f2bf(o[i] * invr[i]);
      }
    }
  }
}

// ---------------- kernel 4: output projection (M=49152, N=256, K=256) -------
__global__ __launch_bounds__(256) void proj_gemm(
    const ushort_t* __restrict__ a_, const ushort_t* __restrict__ w,
    const float* __restrict__ pb, float* __restrict__ out) {
  const int lane = threadIdx.x & 63;
  const int wv = threadIdx.x >> 6;
  const int ln = lane & 15, qd = lane >> 4;
  const int row0 = blockIdx.x * 128 + (wv >> 1) * 64;
  const int col0 = blockIdx.y * 128 + (wv & 1) * 64;

  floatx4 acc[4][4];
  #pragma unroll
  for (int rt = 0; rt < 4; ++rt)
    #pragma unroll
    for (int ct = 0; ct < 4; ++ct)
      acc[rt][ct] = floatx4{0.f, 0.f, 0.f, 0.f};

  const ushort_t* ap = a_ + (size_t)(row0 + ln) * 256 + qd * 8;
  const ushort_t* bp = w + (size_t)(col0 + ln) * 256 + qd * 8;

  bf16x8 a[4], b[4], an[4], bn[4];
  #pragma unroll
  for (int t = 0; t < 4; ++t) {
    a[t] = ldg8(ap + t * 16 * 256);
    b[t] = ldg8(bp + t * 16 * 256);
  }
  #pragma unroll
  for (int kt = 0; kt < 8; ++kt) {
    if (kt < 7) {
      #pragma unroll
      for (int t = 0; t < 4; ++t) {
        an[t] = ldg8(ap + t * 16 * 256 + (kt + 1) * 32);
        bn[t] = ldg8(bp + t * 16 * 256 + (kt + 1) * 32);
      }
    }
    #pragma unroll
    for (int rt = 0; rt < 4; ++rt)
      #pragma unroll
      for (int ct = 0; ct < 4; ++ct)
        acc[rt][ct] = __builtin_amdgcn_mfma_f32_16x16x32_bf16(a[rt], b[ct], acc[rt][ct], 0, 0, 0);
    if (kt < 7) {
      #pragma unroll
      for (int t = 0; t < 4; ++t) { a[t] = an[t]; b[t] = bn[t]; }
    }
  }

  #pragma unroll
  for (int ct = 0; ct < 4; ++ct) {
    int colg = col0 + ct * 16 + ln;
    float bcol = pb[colg];
    #pragma unroll
    for (int rt = 0; rt < 4; ++rt) {
      int rbase = row0 + rt * 16 + qd * 4;
      #pragma unroll
      for (int i = 0; i < 4; ++i)
        out[(size_t)(rbase + i) * 256 + colg] = acc[rt][ct][i] + bcol;
    }
  }
}

// ---------------- launch ----------------------------------------------------
extern "C" void kernel_launch(void* const* d_in, const int* in_sizes, int n_in,
                              void* d_out, int out_size, void* d_ws, size_t ws_size,
                              hipStream_t stream) {
  const float* x      = (const float*)d_in[0];
  const float* mask   = (const float*)d_in[1];
  const float* qkv_w  = (const float*)d_in[2];
  const float* qkv_b  = (const float*)d_in[3];
  const float* proj_w = (const float*)d_in[4];
  const float* proj_b = (const float*)d_in[5];
  const float* table  = (const float*)d_in[6];
  const int*   idx    = (const int*)d_in[7];
  float* out = (float*)d_out;

  char* ws = (char*)d_ws;
  const size_t SZ = (size_t)MROWS * CDIM * 2;  // 25165824 B per bf16 buffer
  ushort_t* xbf  = (ushort_t*)(ws);
  ushort_t* qws  = (ushort_t*)(ws + SZ);
  ushort_t* kws  = (ushort_t*)(ws + 2 * SZ);
  ushort_t* vtws = (ushort_t*)(ws + 3 * SZ);
  ushort_t* aows = (ushort_t*)(ws + 4 * SZ);
  ushort_t* bmws = (ushort_t*)(ws + 5 * SZ);                    // 64 MB bf16 (w,h,row,col)
  ushort_t* wqkvbf  = (ushort_t*)(ws + 5 * SZ + 67108864);      // 768x256 bf16
  ushort_t* wprojbf = (ushort_t*)(ws + 5 * SZ + 67108864 + 393216);

  cvt_f32_bf16<<<dim3(6144), dim3(256), 0, stream>>>(x, xbf, 12582912 / 8);
  cvt_f32_bf16<<<dim3(96),   dim3(256), 0, stream>>>(qkv_w, wqkvbf, 196608 / 8);
  cvt_f32_bf16<<<dim3(32),   dim3(256), 0, stream>>>(proj_w, wprojbf, 65536 / 8);
  bm_prep<<<dim3(64, 256), dim3(256), 0, stream>>>(idx, table, mask, bmws);
  qkv_gemm<<<dim3(384, 6), dim3(256), 0, stream>>>(xbf, wqkvbf, qkv_b, qws, kws, vtws);
  attn_kernel<<<dim3(512), dim3(512), 0, stream>>>(qws, kws, vtws, bmws, aows);
  proj_gemm<<<dim3(384, 2), dim3(256), 0, stream>>>(aows, wprojbf, proj_b, out);
}

// Round 5
// 324.676 us; speedup vs baseline: 1.3232x; 1.1466x over previous
//
#include <hip/hip_runtime.h>

typedef unsigned short ushort_t;
typedef __bf16 bf16x8 __attribute__((ext_vector_type(8)));
typedef float floatx4 __attribute__((ext_vector_type(4)));

#define B_WIN 192
#define NTOK 256
#define CDIM 256
#define NHEAD 8
#define HDIM 32
#define NWIN 64
#define MROWS (B_WIN * NTOK)   // 49152

__device__ __forceinline__ float bf2f(unsigned int b) {
  unsigned int u = (b & 0xffffu) << 16;
  float f; __builtin_memcpy(&f, &u, 4); return f;
}
__device__ __forceinline__ ushort_t f2bf(float f) {
  unsigned int u; __builtin_memcpy(&u, &f, 4);
  u = (u + 0x7fffu + ((u >> 16) & 1u)) >> 16;
  return (ushort_t)u;
}
__device__ __forceinline__ bf16x8 ldg8(const ushort_t* p) {
  return *reinterpret_cast<const bf16x8*>(p);
}
__device__ __forceinline__ void async_copy16(const void* g, void* l) {
  __builtin_amdgcn_global_load_lds(
      (const __attribute__((address_space(1))) unsigned int*)g,
      (__attribute__((address_space(3))) unsigned int*)l, 16, 0, 0);
}

// ---------------- kernel 0: fp32 -> bf16 conversion (8 elems/thread) --------
__global__ __launch_bounds__(256) void cvt_f32_bf16(const float* __restrict__ src,
                                                    ushort_t* __restrict__ dst, int n8) {
  int t = blockIdx.x * 256 + threadIdx.x;
  if (t >= n8) return;
  const float4* s = reinterpret_cast<const float4*>(src) + (size_t)t * 2;
  float4 v0 = s[0], v1 = s[1];
  union { ushort_t u[8]; uint4 v; } pk;
  pk.u[0] = f2bf(v0.x); pk.u[1] = f2bf(v0.y); pk.u[2] = f2bf(v0.z); pk.u[3] = f2bf(v0.w);
  pk.u[4] = f2bf(v1.x); pk.u[5] = f2bf(v1.y); pk.u[6] = f2bf(v1.z); pk.u[7] = f2bf(v1.w);
  reinterpret_cast<uint4*>(dst)[t] = pk.v;
}

// ---------------- kernel 1: combined bias+mask, natural layout bf16 ---------
__global__ __launch_bounds__(256) void bm_prep(const int* __restrict__ idx,
                                               const float* __restrict__ table,
                                               const float* __restrict__ mask,
                                               ushort_t* __restrict__ bm) {
  int win = blockIdx.x;     // 0..63
  int row = blockIdx.y;     // 0..255
  int col = threadIdx.x;    // 0..255
  int id = idx[row * 256 + col];
  float mval = mask[((size_t)(win * 256 + row) << 8) + col];
  #pragma unroll
  for (int h = 0; h < NHEAD; ++h) {
    float b = table[id * NHEAD + h];
    bm[((((size_t)win * NHEAD + h) * 256 + row) << 8) + col] = f2bf(b + mval);
  }
}

// ---------------- kernel 2: QKV GEMM  (M=49152, N=768, K=256), B^T input -----
// Epilogue writes k and v in MFMA-tile order so attn can async-stage them to
// LDS contiguously AND read frags as lane-sequential b128 (conflict-free):
//   k_tiled[bh]: elem(tok,d) -> ((tok>>4)*4 + (d>>3))*128 + (tok&15)*8 + (d&7)
//   v_tiled[bh]: elem(tok,d) -> ((tok>>5)*8 + ((tok>>3)&3)*2 + (d>>4))*128
//                               + (d&15)*8 + (tok&7)
__global__ __launch_bounds__(256) void qkv_gemm(
    const ushort_t* __restrict__ x, const ushort_t* __restrict__ w,
    const float* __restrict__ qkvb, ushort_t* __restrict__ qws,
    ushort_t* __restrict__ kws, ushort_t* __restrict__ vtws) {
  const int lane = threadIdx.x & 63;
  const int wv = threadIdx.x >> 6;
  const int ln = lane & 15, qd = lane >> 4;
  const int row0 = blockIdx.x * 128 + (wv >> 1) * 64;
  const int col0 = blockIdx.y * 128 + (wv & 1) * 64;

  floatx4 acc[4][4];
  #pragma unroll
  for (int rt = 0; rt < 4; ++rt)
    #pragma unroll
    for (int ct = 0; ct < 4; ++ct)
      acc[rt][ct] = floatx4{0.f, 0.f, 0.f, 0.f};

  const ushort_t* ap = x + (size_t)(row0 + ln) * 256 + qd * 8;
  const ushort_t* bp = w + (size_t)(col0 + ln) * 256 + qd * 8;

  bf16x8 a[4], b[4], an[4], bn[4];
  #pragma unroll
  for (int t = 0; t < 4; ++t) {
    a[t] = ldg8(ap + t * 16 * 256);
    b[t] = ldg8(bp + t * 16 * 256);
  }
  #pragma unroll
  for (int kt = 0; kt < 8; ++kt) {
    if (kt < 7) {
      #pragma unroll
      for (int t = 0; t < 4; ++t) {
        an[t] = ldg8(ap + t * 16 * 256 + (kt + 1) * 32);
        bn[t] = ldg8(bp + t * 16 * 256 + (kt + 1) * 32);
      }
    }
    #pragma unroll
    for (int rt = 0; rt < 4; ++rt)
      #pragma unroll
      for (int ct = 0; ct < 4; ++ct)
        acc[rt][ct] = __builtin_amdgcn_mfma_f32_16x16x32_bf16(a[rt], b[ct], acc[rt][ct], 0, 0, 0);
    if (kt < 7) {
      #pragma unroll
      for (int t = 0; t < 4; ++t) { a[t] = an[t]; b[t] = bn[t]; }
    }
  }

  const int s = col0 >> 8;  // 0=q, 1=k, 2=v — uniform per wave
  const float scl = 0.17677669529663687f;  // 1/sqrt(32)
  #pragma unroll
  for (int ct = 0; ct < 4; ++ct) {
    int colg = col0 + ct * 16 + ln;
    float bcol = qkvb[colg];
    int h = (colg >> 5) & 7;
    int d = colg & 31;
    #pragma unroll
    for (int rt = 0; rt < 4; ++rt) {
      int rbase = row0 + rt * 16 + qd * 4;
      int bwin = rbase >> 8;
      int tok0 = rbase & 255;               // = 16*T + qd*4
      size_t slab = (size_t)(bwin * 8 + h) * 8192;
      if (s == 2) {
        union { ushort_t u[4]; uint2 v; } pk;
        #pragma unroll
        for (int i = 0; i < 4; ++i) pk.u[i] = f2bf(acc[rt][ct][i] + bcol);
        size_t base = slab + (size_t)(((tok0 >> 5) * 4 + ((tok0 >> 3) & 3)) * 2 + (d >> 4)) * 128
                      + (d & 15) * 8 + (tok0 & 7);
        *reinterpret_cast<uint2*>(vtws + base) = pk.v;
      } else if (s == 0) {
        #pragma unroll
        for (int i = 0; i < 4; ++i)
          qws[((size_t)((bwin * 8 + h) * 256 + tok0 + i) << 5) + d] =
              f2bf((acc[rt][ct][i] + bcol) * scl);
      } else {
        size_t base = slab + (size_t)((tok0 >> 4) * 4 + (d >> 3)) * 128 + (d & 7);
        #pragma unroll
        for (int i = 0; i < 4; ++i)
          kws[base + (size_t)((tok0 & 15) + i) * 8] = f2bf(acc[rt][ct][i] + bcol);
      }
    }
  }
}

// ---------------- kernel 3: windowed attention ------------------------------
// One block per (batch,win,h), batch-fastest ordering (bm slice locality).
// k,v async-staged to LDS once per block in MFMA-tile order; frag reads are
// lane-sequential b128. P transpose done with register shuffles (no LDS).
__global__ __launch_bounds__(512, 4) void attn_kernel(
    const ushort_t* __restrict__ qws, const ushort_t* __restrict__ kt_,
    const ushort_t* __restrict__ vt_, const ushort_t* __restrict__ bm,
    ushort_t* __restrict__ aows) {
  __shared__ __align__(16) ushort_t lds_kv[16384];   // k: [0,8192), v: [8192,16384) elems
  const int lane = threadIdx.x & 63;
  const int wv = threadIdx.x >> 6;          // 0..7
  const int ln = lane & 15, qd = lane >> 4;
  const int t = blockIdx.x;
  const int batch = t % 3;
  const int wh = t / 3;                     // win*8 + h
  const int win = wh >> 3, h = wh & 7;
  const int bwin = batch * 64 + win;
  const int bh = bwin * 8 + h;

  // stage k (16KB) + v (16KB)
  {
    const char* kg = (const char*)(kt_ + (size_t)bh * 8192);
    const char* vg = (const char*)(vt_ + (size_t)bh * 8192);
    #pragma unroll
    for (int r = 0; r < 2; ++r) {
      int off = r * 8192 + wv * 1024;
      async_copy16(kg + off + lane * 16, (char*)lds_kv + off);
      async_copy16(vg + off + lane * 16, (char*)lds_kv + 16384 + off);
    }
  }
  __syncthreads();

  const ushort_t* qb = qws + (size_t)bh * 8192;
  const ushort_t* bmp = bm + ((size_t)(win * 8 + h) << 16);

  #pragma unroll
  for (int half = 0; half < 2; ++half) {
    const int m0 = half * 128 + wv * 16;

    // S^T: st[f][i] = S[q = m0+ln][k = f*16 + qd*4 + i]
    bf16x8 qf = ldg8(qb + (m0 + ln) * 32 + qd * 8);
    floatx4 st[16];
    #pragma unroll
    for (int f = 0; f < 16; ++f) {
      bf16x8 kf = *reinterpret_cast<const bf16x8*>(&lds_kv[(f * 64 + lane) * 8]);
      floatx4 z = {0.f, 0.f, 0.f, 0.f};
      st[f] = __builtin_amdgcn_mfma_f32_16x16x32_bf16(kf, qf, z, 0, 0, 0);
    }

    // + (bias+mask), natural layout, 4 k-consecutive bf16 per uint2
    const ushort_t* bmr = bmp + ((m0 + ln) << 8);
    #pragma unroll
    for (int f = 0; f < 16; ++f) {
      uint2 raw = *reinterpret_cast<const uint2*>(bmr + f * 16 + qd * 4);
      st[f][0] += bf2f(raw.x);
      st[f][1] += bf2f(raw.x >> 16);
      st[f][2] += bf2f(raw.y);
      st[f][3] += bf2f(raw.y >> 16);
    }

    // row softmax: in-lane 64-value reduce + xor-16/32 across qd groups
    float mx = -1e30f;
    #pragma unroll
    for (int f = 0; f < 16; ++f)
      mx = fmaxf(mx, fmaxf(fmaxf(st[f][0], st[f][1]), fmaxf(st[f][2], st[f][3])));
    mx = fmaxf(mx, __shfl_xor(mx, 16, 64));
    mx = fmaxf(mx, __shfl_xor(mx, 32, 64));
    float sum = 0.f;
    #pragma unroll
    for (int f = 0; f < 16; ++f) {
      #pragma unroll
      for (int i = 0; i < 4; ++i) {
        float e = __expf(st[f][i] - mx);
        st[f][i] = e;
        sum += e;
      }
    }
    sum += __shfl_xor(sum, 16, 64);
    sum += __shfl_xor(sum, 32, 64);
    float inv = 1.0f / sum;   // applied post-PV

    // pack unnormalized P quartets: pk[f] = P[q=ln][k=f*16+qd*4 .. +3]
    uint2 pk[16];
    #pragma unroll
    for (int f = 0; f < 16; ++f) {
      union { ushort_t u[4]; uint2 v; } p;
      p.u[0] = f2bf(st[f][0]); p.u[1] = f2bf(st[f][1]);
      p.u[2] = f2bf(st[f][2]); p.u[3] = f2bf(st[f][3]);
      pk[f] = p.v;
    }

    float invr[4];
    #pragma unroll
    for (int i = 0; i < 4; ++i) invr[i] = __shfl(inv, qd * 4 + i, 16);

    // shuffle-transpose P into A-frag layout per 32-wide k-tile, then PV
    const int lane_lo = ((qd & 1) << 5) + ln;   // src lane for quartet J=8kt+2qd
    const int lane_hi = lane_lo + 16;           // src lane for quartet J+1
    const bool fsel = (qd >> 1) != 0;           // which pk reg at the source
    floatx4 o[2];
    o[0] = floatx4{0.f, 0.f, 0.f, 0.f};
    o[1] = floatx4{0.f, 0.f, 0.f, 0.f};
    #pragma unroll
    for (int kt = 0; kt < 8; ++kt) {
      unsigned e0x = pk[2 * kt].x, e0y = pk[2 * kt].y;
      unsigned e1x = pk[2 * kt + 1].x, e1y = pk[2 * kt + 1].y;
      unsigned s0x = __shfl((int)e0x, lane_lo, 64), s0y = __shfl((int)e0y, lane_lo, 64);
      unsigned s1x = __shfl((int)e1x, lane_lo, 64), s1y = __shfl((int)e1y, lane_lo, 64);
      unsigned t0x = __shfl((int)e0x, lane_hi, 64), t0y = __shfl((int)e0y, lane_hi, 64);
      unsigned t1x = __shfl((int)e1x, lane_hi, 64), t1y = __shfl((int)e1y, lane_hi, 64);
      union { unsigned u[4]; bf16x8 v; } af;
      af.u[0] = fsel ? s1x : s0x;
      af.u[1] = fsel ? s1y : s0y;
      af.u[2] = fsel ? t1x : t0x;
      af.u[3] = fsel ? t1y : t0y;
      #pragma unroll
      for (int nt = 0; nt < 2; ++nt) {
        bf16x8 bv = *reinterpret_cast<const bf16x8*>(
            &lds_kv[8192 + (kt * 128 + qd * 32 + nt * 16 + ln) * 8]);
        o[nt] = __builtin_amdgcn_mfma_f32_16x16x32_bf16(af.v, bv, o[nt], 0, 0, 0);
      }
    }

    #pragma unroll
    for (int nt = 0; nt < 2; ++nt)
      #pragma unroll
      for (int i = 0; i < 4; ++i) {
        int tok = m0 + qd * 4 + i;
        aows[((size_t)(bwin * 256 + tok) << 8) + h * 32 + nt * 16 + ln] =
            f2bf(o[nt][i] * invr[i]);
      }
  }
}

// ---------------- kernel 4: output projection (M=49152, N=256, K=256) -------
__global__ __launch_bounds__(256) void proj_gemm(
    const ushort_t* __restrict__ a_, const ushort_t* __restrict__ w,
    const float* __restrict__ pb, float* __restrict__ out) {
  const int lane = threadIdx.x & 63;
  const int wv = threadIdx.x >> 6;
  const int ln = lane & 15, qd = lane >> 4;
  const int row0 = blockIdx.x * 128 + (wv >> 1) * 64;
  const int col0 = blockIdx.y * 128 + (wv & 1) * 64;

  floatx4 acc[4][4];
  #pragma unroll
  for (int rt = 0; rt < 4; ++rt)
    #pragma unroll
    for (int ct = 0; ct < 4; ++ct)
      acc[rt][ct] = floatx4{0.f, 0.f, 0.f, 0.f};

  const ushort_t* ap = a_ + (size_t)(row0 + ln) * 256 + qd * 8;
  const ushort_t* bp = w + (size_t)(col0 + ln) * 256 + qd * 8;

  bf16x8 a[4], b[4], an[4], bn[4];
  #pragma unroll
  for (int t = 0; t < 4; ++t) {
    a[t] = ldg8(ap + t * 16 * 256);
    b[t] = ldg8(bp + t * 16 * 256);
  }
  #pragma unroll
  for (int kt = 0; kt < 8; ++kt) {
    if (kt < 7) {
      #pragma unroll
      for (int t = 0; t < 4; ++t) {
        an[t] = ldg8(ap + t * 16 * 256 + (kt + 1) * 32);
        bn[t] = ldg8(bp + t * 16 * 256 + (kt + 1) * 32);
      }
    }
    #pragma unroll
    for (int rt = 0; rt < 4; ++rt)
      #pragma unroll
      for (int ct = 0; ct < 4; ++ct)
        acc[rt][ct] = __builtin_amdgcn_mfma_f32_16x16x32_bf16(a[rt], b[ct], acc[rt][ct], 0, 0, 0);
    if (kt < 7) {
      #pragma unroll
      for (int t = 0; t < 4; ++t) { a[t] = an[t]; b[t] = bn[t]; }
    }
  }

  #pragma unroll
  for (int ct = 0; ct < 4; ++ct) {
    int colg = col0 + ct * 16 + ln;
    float bcol = pb[colg];
    #pragma unroll
    for (int rt = 0; rt < 4; ++rt) {
      int rbase = row0 + rt * 16 + qd * 4;
      #pragma unroll
      for (int i = 0; i < 4; ++i)
        out[(size_t)(rbase + i) * 256 + colg] = acc[rt][ct][i] + bcol;
    }
  }
}

// ---------------- launch ----------------------------------------------------
extern "C" void kernel_launch(void* const* d_in, const int* in_sizes, int n_in,
                              void* d_out, int out_size, void* d_ws, size_t ws_size,
                              hipStream_t stream) {
  const float* x      = (const float*)d_in[0];
  const float* mask   = (const float*)d_in[1];
  const float* qkv_w  = (const float*)d_in[2];
  const float* qkv_b  = (const float*)d_in[3];
  const float* proj_w = (const float*)d_in[4];
  const float* proj_b = (const float*)d_in[5];
  const float* table  = (const float*)d_in[6];
  const int*   idx    = (const int*)d_in[7];
  float* out = (float*)d_out;

  char* ws = (char*)d_ws;
  const size_t SZ = (size_t)MROWS * CDIM * 2;  // 25165824 B per bf16 buffer
  ushort_t* xbf  = (ushort_t*)(ws);
  ushort_t* qws  = (ushort_t*)(ws + SZ);
  ushort_t* kws  = (ushort_t*)(ws + 2 * SZ);   // k_tiled
  ushort_t* vtws = (ushort_t*)(ws + 3 * SZ);   // v_tiled
  ushort_t* aows = (ushort_t*)(ws + 4 * SZ);
  ushort_t* bmws = (ushort_t*)(ws + 5 * SZ);                    // 64 MB bf16 (w,h,row,col)
  ushort_t* wqkvbf  = (ushort_t*)(ws + 5 * SZ + 67108864);      // 768x256 bf16
  ushort_t* wprojbf = (ushort_t*)(ws + 5 * SZ + 67108864 + 393216);

  cvt_f32_bf16<<<dim3(6144), dim3(256), 0, stream>>>(x, xbf, 12582912 / 8);
  cvt_f32_bf16<<<dim3(96),   dim3(256), 0, stream>>>(qkv_w, wqkvbf, 196608 / 8);
  cvt_f32_bf16<<<dim3(32),   dim3(256), 0, stream>>>(proj_w, wprojbf, 65536 / 8);
  bm_prep<<<dim3(64, 256), dim3(256), 0, stream>>>(idx, table, mask, bmws);
  qkv_gemm<<<dim3(384, 6), dim3(256), 0, stream>>>(xbf, wqkvbf, qkv_b, qws, kws, vtws);
  attn_kernel<<<dim3(1536), dim3(512), 0, stream>>>(qws, kws, vtws, bmws, aows);
  proj_gemm<<<dim3(384, 2), dim3(256), 0, stream>>>(aows, wprojbf, proj_b, out);
}

// Round 6
// 301.018 us; speedup vs baseline: 1.4271x; 1.0786x over previous
//
#include <hip/hip_runtime.h>

typedef unsigned short ushort_t;
typedef __bf16 bf16x8 __attribute__((ext_vector_type(8)));
typedef float floatx4 __attribute__((ext_vector_type(4)));

#define B_WIN 192
#define NTOK 256
#define CDIM 256
#define NHEAD 8
#define HDIM 32
#define NWIN 64
#define MROWS (B_WIN * NTOK)   // 49152

__device__ __forceinline__ float bf2f(unsigned int b) {
  unsigned int u = (b & 0xffffu) << 16;
  float f; __builtin_memcpy(&f, &u, 4); return f;
}
__device__ __forceinline__ ushort_t f2bf(float f) {
  unsigned int u; __builtin_memcpy(&u, &f, 4);
  u = (u + 0x7fffu + ((u >> 16) & 1u)) >> 16;
  return (ushort_t)u;
}
__device__ __forceinline__ bf16x8 ldg8(const ushort_t* p) {
  return *reinterpret_cast<const bf16x8*>(p);
}
__device__ __forceinline__ void async_copy16(const void* g, void* l) {
  __builtin_amdgcn_global_load_lds(
      (const __attribute__((address_space(1))) unsigned int*)g,
      (__attribute__((address_space(3))) unsigned int*)l, 16, 0, 0);
}

// ---------------- kernel 0a: fp32 -> bf16 conversion (8 elems/thread) -------
__global__ __launch_bounds__(256) void cvt_f32_bf16(const float* __restrict__ src,
                                                    ushort_t* __restrict__ dst, int n8) {
  int t = blockIdx.x * 256 + threadIdx.x;
  if (t >= n8) return;
  const float4* s = reinterpret_cast<const float4*>(src) + (size_t)t * 2;
  float4 v0 = s[0], v1 = s[1];
  union { ushort_t u[8]; uint4 v; } pk;
  pk.u[0] = f2bf(v0.x); pk.u[1] = f2bf(v0.y); pk.u[2] = f2bf(v0.z); pk.u[3] = f2bf(v0.w);
  pk.u[4] = f2bf(v1.x); pk.u[5] = f2bf(v1.y); pk.u[6] = f2bf(v1.z); pk.u[7] = f2bf(v1.w);
  reinterpret_cast<uint4*>(dst)[t] = pk.v;
}

// ---------------- kernel 0b: fp32 weights -> bf16 MFMA-TILED ----------------
// dst elem(col,k) -> ((col>>4)*8 + (k>>5))*512 + ((k>>3)&3)*128 + (col&15)*8 + (k&7)
// so a 128-col x 256-K slab is one contiguous 64KB run (async-stageable) and
// frag reads from LDS are lane-sequential b128 (conflict-free).
__global__ __launch_bounds__(256) void cvt_tile_w(const float* __restrict__ src,
                                                  ushort_t* __restrict__ dst, int n) {
  int t = blockIdx.x * 256 + threadIdx.x;
  if (t >= n) return;                       // n = NC*32 threads, 8 k-elems each
  int col = t >> 5;
  int kk = (t & 31) * 8;
  const float4* s = reinterpret_cast<const float4*>(src + (size_t)col * 256 + kk);
  float4 v0 = s[0], v1 = s[1];
  union { ushort_t u[8]; uint4 v; } pk;
  pk.u[0] = f2bf(v0.x); pk.u[1] = f2bf(v0.y); pk.u[2] = f2bf(v0.z); pk.u[3] = f2bf(v0.w);
  pk.u[4] = f2bf(v1.x); pk.u[5] = f2bf(v1.y); pk.u[6] = f2bf(v1.z); pk.u[7] = f2bf(v1.w);
  size_t base = (size_t)(((col >> 4) * 8 + (kk >> 5)) * 512 + ((kk >> 3) & 3) * 128 + (col & 15) * 8);
  *reinterpret_cast<uint4*>(dst + base) = pk.v;
}

// ---------------- kernel 1: combined bias+mask, natural layout bf16 ---------
__global__ __launch_bounds__(256) void bm_prep(const int* __restrict__ idx,
                                               const float* __restrict__ table,
                                               const float* __restrict__ mask,
                                               ushort_t* __restrict__ bm) {
  int win = blockIdx.x;     // 0..63
  int row = blockIdx.y;     // 0..255
  int col = threadIdx.x;    // 0..255
  int id = idx[row * 256 + col];
  float mval = mask[((size_t)(win * 256 + row) << 8) + col];
  #pragma unroll
  for (int h = 0; h < NHEAD; ++h) {
    float b = table[id * NHEAD + h];
    bm[((((size_t)win * NHEAD + h) * 256 + row) << 8) + col] = f2bf(b + mval);
  }
}

// ---------------- kernel 2: QKV GEMM, B staged in LDS -----------------------
// B slab (128 cols x 256 K, tiled order) async-staged once; K-loop reads B
// from LDS (conflict-free b128) and streams A from global with depth-2
// prefetch. Epilogue scatters q / k_tiled / v_tiled as before.
__global__ __launch_bounds__(256) void qkv_gemm(
    const ushort_t* __restrict__ x, const ushort_t* __restrict__ wt,
    const float* __restrict__ qkvb, ushort_t* __restrict__ qws,
    ushort_t* __restrict__ kws, ushort_t* __restrict__ vtws) {
  __shared__ __align__(16) ushort_t bsh[128 * 256];   // 64 KB
  const int lane = threadIdx.x & 63;
  const int wv = threadIdx.x >> 6;
  const int ln = lane & 15, qd = lane >> 4;
  const int row0 = blockIdx.x * 128 + (wv >> 1) * 64;
  const int col0 = blockIdx.y * 128;
  const int colw = col0 + (wv & 1) * 64;

  {
    const char* g = (const char*)(wt + (size_t)col0 * 256);
    #pragma unroll
    for (int r = 0; r < 16; ++r) {
      int off = r * 4096 + wv * 1024;
      async_copy16(g + off + lane * 16, (char*)bsh + off);
    }
  }
  __syncthreads();

  floatx4 acc[4][4];
  #pragma unroll
  for (int rt = 0; rt < 4; ++rt)
    #pragma unroll
    for (int ct = 0; ct < 4; ++ct)
      acc[rt][ct] = floatx4{0.f, 0.f, 0.f, 0.f};

  const ushort_t* ap = x + (size_t)(row0 + ln) * 256 + qd * 8;
  bf16x8 abuf[2][4];
  #pragma unroll
  for (int t = 0; t < 4; ++t) {
    abuf[0][t] = ldg8(ap + t * 16 * 256);
    abuf[1][t] = ldg8(ap + t * 16 * 256 + 32);
  }

  #pragma unroll
  for (int kt = 0; kt < 8; ++kt) {
    bf16x8 bb[4];
    #pragma unroll
    for (int ct = 0; ct < 4; ++ct)
      bb[ct] = *reinterpret_cast<const bf16x8*>(
          &bsh[(((wv & 1) * 4 + ct) * 8 + kt) * 512 + qd * 128 + ln * 8]);
    #pragma unroll
    for (int rt = 0; rt < 4; ++rt)
      #pragma unroll
      for (int ct = 0; ct < 4; ++ct)
        acc[rt][ct] = __builtin_amdgcn_mfma_f32_16x16x32_bf16(abuf[kt & 1][rt], bb[ct],
                                                              acc[rt][ct], 0, 0, 0);
    if (kt < 6) {
      #pragma unroll
      for (int t = 0; t < 4; ++t)
        abuf[kt & 1][t] = ldg8(ap + t * 16 * 256 + (kt + 2) * 32);
    }
  }

  const int s = colw >> 8;  // 0=q, 1=k, 2=v — uniform per wave
  const float scl = 0.17677669529663687f;  // 1/sqrt(32)
  #pragma unroll
  for (int ct = 0; ct < 4; ++ct) {
    int colg = colw + ct * 16 + ln;
    float bcol = qkvb[colg];
    int h = (colg >> 5) & 7;
    int d = colg & 31;
    #pragma unroll
    for (int rt = 0; rt < 4; ++rt) {
      int rbase = row0 + rt * 16 + qd * 4;
      int bwin = rbase >> 8;
      int tok0 = rbase & 255;
      size_t slab = (size_t)(bwin * 8 + h) * 8192;
      if (s == 2) {
        union { ushort_t u[4]; uint2 v; } pk;
        #pragma unroll
        for (int i = 0; i < 4; ++i) pk.u[i] = f2bf(acc[rt][ct][i] + bcol);
        size_t base = slab + (size_t)(((tok0 >> 5) * 4 + ((tok0 >> 3) & 3)) * 2 + (d >> 4)) * 128
                      + (d & 15) * 8 + (tok0 & 7);
        *reinterpret_cast<uint2*>(vtws + base) = pk.v;
      } else if (s == 0) {
        #pragma unroll
        for (int i = 0; i < 4; ++i)
          qws[((size_t)((bwin * 8 + h) * 256 + tok0 + i) << 5) + d] =
              f2bf((acc[rt][ct][i] + bcol) * scl);
      } else {
        size_t base = slab + (size_t)((tok0 >> 4) * 4 + (d >> 3)) * 128 + (d & 7);
        #pragma unroll
        for (int i = 0; i < 4; ++i)
          kws[base + (size_t)((tok0 & 15) + i) * 8] = f2bf(acc[rt][ct][i] + bcol);
      }
    }
  }
}

// ---------------- kernel 3: windowed attention (unchanged from R5) ----------
__global__ __launch_bounds__(512, 4) void attn_kernel(
    const ushort_t* __restrict__ qws, const ushort_t* __restrict__ kt_,
    const ushort_t* __restrict__ vt_, const ushort_t* __restrict__ bm,
    ushort_t* __restrict__ aows) {
  __shared__ __align__(16) ushort_t lds_kv[16384];
  const int lane = threadIdx.x & 63;
  const int wv = threadIdx.x >> 6;
  const int ln = lane & 15, qd = lane >> 4;
  const int t = blockIdx.x;
  const int batch = t % 3;
  const int wh = t / 3;
  const int win = wh >> 3, h = wh & 7;
  const int bwin = batch * 64 + win;
  const int bh = bwin * 8 + h;

  {
    const char* kg = (const char*)(kt_ + (size_t)bh * 8192);
    const char* vg = (const char*)(vt_ + (size_t)bh * 8192);
    #pragma unroll
    for (int r = 0; r < 2; ++r) {
      int off = r * 8192 + wv * 1024;
      async_copy16(kg + off + lane * 16, (char*)lds_kv + off);
      async_copy16(vg + off + lane * 16, (char*)lds_kv + 16384 + off);
    }
  }
  __syncthreads();

  const ushort_t* qb = qws + (size_t)bh * 8192;
  const ushort_t* bmp = bm + ((size_t)(win * 8 + h) << 16);

  #pragma unroll
  for (int half = 0; half < 2; ++half) {
    const int m0 = half * 128 + wv * 16;

    bf16x8 qf = ldg8(qb + (m0 + ln) * 32 + qd * 8);
    floatx4 st[16];
    #pragma unroll
    for (int f = 0; f < 16; ++f) {
      bf16x8 kf = *reinterpret_cast<const bf16x8*>(&lds_kv[(f * 64 + lane) * 8]);
      floatx4 z = {0.f, 0.f, 0.f, 0.f};
      st[f] = __builtin_amdgcn_mfma_f32_16x16x32_bf16(kf, qf, z, 0, 0, 0);
    }

    const ushort_t* bmr = bmp + ((m0 + ln) << 8);
    #pragma unroll
    for (int f = 0; f < 16; ++f) {
      uint2 raw = *reinterpret_cast<const uint2*>(bmr + f * 16 + qd * 4);
      st[f][0] += bf2f(raw.x);
      st[f][1] += bf2f(raw.x >> 16);
      st[f][2] += bf2f(raw.y);
      st[f][3] += bf2f(raw.y >> 16);
    }

    float mx = -1e30f;
    #pragma unroll
    for (int f = 0; f < 16; ++f)
      mx = fmaxf(mx, fmaxf(fmaxf(st[f][0], st[f][1]), fmaxf(st[f][2], st[f][3])));
    mx = fmaxf(mx, __shfl_xor(mx, 16, 64));
    mx = fmaxf(mx, __shfl_xor(mx, 32, 64));
    float sum = 0.f;
    #pragma unroll
    for (int f = 0; f < 16; ++f) {
      #pragma unroll
      for (int i = 0; i < 4; ++i) {
        float e = __expf(st[f][i] - mx);
        st[f][i] = e;
        sum += e;
      }
    }
    sum += __shfl_xor(sum, 16, 64);
    sum += __shfl_xor(sum, 32, 64);
    float inv = 1.0f / sum;

    uint2 pk[16];
    #pragma unroll
    for (int f = 0; f < 16; ++f) {
      union { ushort_t u[4]; uint2 v; } p;
      p.u[0] = f2bf(st[f][0]); p.u[1] = f2bf(st[f][1]);
      p.u[2] = f2bf(st[f][2]); p.u[3] = f2bf(st[f][3]);
      pk[f] = p.v;
    }

    float invr[4];
    #pragma unroll
    for (int i = 0; i < 4; ++i) invr[i] = __shfl(inv, qd * 4 + i, 16);

    const int lane_lo = ((qd & 1) << 5) + ln;
    const int lane_hi = lane_lo + 16;
    const bool fsel = (qd >> 1) != 0;
    floatx4 o[2];
    o[0] = floatx4{0.f, 0.f, 0.f, 0.f};
    o[1] = floatx4{0.f, 0.f, 0.f, 0.f};
    #pragma unroll
    for (int kt = 0; kt < 8; ++kt) {
      unsigned e0x = pk[2 * kt].x, e0y = pk[2 * kt].y;
      unsigned e1x = pk[2 * kt + 1].x, e1y = pk[2 * kt + 1].y;
      unsigned s0x = __shfl((int)e0x, lane_lo, 64), s0y = __shfl((int)e0y, lane_lo, 64);
      unsigned s1x = __shfl((int)e1x, lane_lo, 64), s1y = __shfl((int)e1y, lane_lo, 64);
      unsigned t0x = __shfl((int)e0x, lane_hi, 64), t0y = __shfl((int)e0y, lane_hi, 64);
      unsigned t1x = __shfl((int)e1x, lane_hi, 64), t1y = __shfl((int)e1y, lane_hi, 64);
      union { unsigned u[4]; bf16x8 v; } af;
      af.u[0] = fsel ? s1x : s0x;
      af.u[1] = fsel ? s1y : s0y;
      af.u[2] = fsel ? t1x : t0x;
      af.u[3] = fsel ? t1y : t0y;
      #pragma unroll
      for (int nt = 0; nt < 2; ++nt) {
        bf16x8 bv = *reinterpret_cast<const bf16x8*>(
            &lds_kv[8192 + (kt * 128 + qd * 32 + nt * 16 + ln) * 8]);
        o[nt] = __builtin_amdgcn_mfma_f32_16x16x32_bf16(af.v, bv, o[nt], 0, 0, 0);
      }
    }

    #pragma unroll
    for (int nt = 0; nt < 2; ++nt)
      #pragma unroll
      for (int i = 0; i < 4; ++i) {
        int tok = m0 + qd * 4 + i;
        aows[((size_t)(bwin * 256 + tok) << 8) + h * 32 + nt * 16 + ln] =
            f2bf(o[nt][i] * invr[i]);
      }
  }
}

// ---------------- kernel 4: output projection, B staged in LDS --------------
__global__ __launch_bounds__(256) void proj_gemm(
    const ushort_t* __restrict__ a_, const ushort_t* __restrict__ wt,
    const float* __restrict__ pb, float* __restrict__ out) {
  __shared__ __align__(16) ushort_t bsh[128 * 256];   // 64 KB
  const int lane = threadIdx.x & 63;
  const int wv = threadIdx.x >> 6;
  const int ln = lane & 15, qd = lane >> 4;
  const int row0 = blockIdx.x * 128 + (wv >> 1) * 64;
  const int col0 = blockIdx.y * 128;
  const int colw = col0 + (wv & 1) * 64;

  {
    const char* g = (const char*)(wt + (size_t)col0 * 256);
    #pragma unroll
    for (int r = 0; r < 16; ++r) {
      int off = r * 4096 + wv * 1024;
      async_copy16(g + off + lane * 16, (char*)bsh + off);
    }
  }
  __syncthreads();

  floatx4 acc[4][4];
  #pragma unroll
  for (int rt = 0; rt < 4; ++rt)
    #pragma unroll
    for (int ct = 0; ct < 4; ++ct)
      acc[rt][ct] = floatx4{0.f, 0.f, 0.f, 0.f};

  const ushort_t* ap = a_ + (size_t)(row0 + ln) * 256 + qd * 8;
  bf16x8 abuf[2][4];
  #pragma unroll
  for (int t = 0; t < 4; ++t) {
    abuf[0][t] = ldg8(ap + t * 16 * 256);
    abuf[1][t] = ldg8(ap + t * 16 * 256 + 32);
  }

  #pragma unroll
  for (int kt = 0; kt < 8; ++kt) {
    bf16x8 bb[4];
    #pragma unroll
    for (int ct = 0; ct < 4; ++ct)
      bb[ct] = *reinterpret_cast<const bf16x8*>(
          &bsh[(((wv & 1) * 4 + ct) * 8 + kt) * 512 + qd * 128 + ln * 8]);
    #pragma unroll
    for (int rt = 0; rt < 4; ++rt)
      #pragma unroll
      for (int ct = 0; ct < 4; ++ct)
        acc[rt][ct] = __builtin_amdgcn_mfma_f32_16x16x32_bf16(abuf[kt & 1][rt], bb[ct],
                                                              acc[rt][ct], 0, 0, 0);
    if (kt < 6) {
      #pragma unroll
      for (int t = 0; t < 4; ++t)
        abuf[kt & 1][t] = ldg8(ap + t * 16 * 256 + (kt + 2) * 32);
    }
  }

  #pragma unroll
  for (int ct = 0; ct < 4; ++ct) {
    int colg = colw + ct * 16 + ln;
    float bcol = pb[colg];
    #pragma unroll
    for (int rt = 0; rt < 4; ++rt) {
      int rbase = row0 + rt * 16 + qd * 4;
      #pragma unroll
      for (int i = 0; i < 4; ++i)
        out[(size_t)(rbase + i) * 256 + colg] = acc[rt][ct][i] + bcol;
    }
  }
}

// ---------------- launch ----------------------------------------------------
extern "C" void kernel_launch(void* const* d_in, const int* in_sizes, int n_in,
                              void* d_out, int out_size, void* d_ws, size_t ws_size,
                              hipStream_t stream) {
  const float* x      = (const float*)d_in[0];
  const float* mask   = (const float*)d_in[1];
  const float* qkv_w  = (const float*)d_in[2];
  const float* qkv_b  = (const float*)d_in[3];
  const float* proj_w = (const float*)d_in[4];
  const float* proj_b = (const float*)d_in[5];
  const float* table  = (const float*)d_in[6];
  const int*   idx    = (const int*)d_in[7];
  float* out = (float*)d_out;

  char* ws = (char*)d_ws;
  const size_t SZ = (size_t)MROWS * CDIM * 2;  // 25165824 B per bf16 buffer
  ushort_t* xbf  = (ushort_t*)(ws);
  ushort_t* qws  = (ushort_t*)(ws + SZ);
  ushort_t* kws  = (ushort_t*)(ws + 2 * SZ);   // k_tiled
  ushort_t* vtws = (ushort_t*)(ws + 3 * SZ);   // v_tiled
  ushort_t* aows = (ushort_t*)(ws + 4 * SZ);
  ushort_t* bmws = (ushort_t*)(ws + 5 * SZ);                    // 64 MB bf16
  ushort_t* wqkvbf  = (ushort_t*)(ws + 5 * SZ + 67108864);      // tiled 768x256 bf16
  ushort_t* wprojbf = (ushort_t*)(ws + 5 * SZ + 67108864 + 393216);

  cvt_f32_bf16<<<dim3(6144), dim3(256), 0, stream>>>(x, xbf, 12582912 / 8);
  cvt_tile_w<<<dim3(96), dim3(256), 0, stream>>>(qkv_w, wqkvbf, 768 * 32);
  cvt_tile_w<<<dim3(32), dim3(256), 0, stream>>>(proj_w, wprojbf, 256 * 32);
  bm_prep<<<dim3(64, 256), dim3(256), 0, stream>>>(idx, table, mask, bmws);
  qkv_gemm<<<dim3(384, 6), dim3(256), 0, stream>>>(xbf, wqkvbf, qkv_b, qws, kws, vtws);
  attn_kernel<<<dim3(1536), dim3(512), 0, stream>>>(qws, kws, vtws, bmws, aows);
  proj_gemm<<<dim3(384, 2), dim3(256), 0, stream>>>(aows, wprojbf, proj_b, out);
}